// Round 1
// baseline (516.028 us; speedup 1.0000x reference)
//
#include <hip/hip_runtime.h>

// MultiHeadAttention: B=8, S=256, D=4096, H=16, HD=256 (fp32 in/out)
// Pipeline: fp32->fp16 converts; Q/K/V projections via fp16 MFMA GEMM
// (fp32 accum); attention per (head, 64-row block); O-projection -> fp32 out.

typedef _Float16 f16;
typedef f16 f16x8 __attribute__((ext_vector_type(8)));
typedef float f32x4 __attribute__((ext_vector_type(4)));

__device__ __forceinline__ void g2lds(const f16* g, f16* l) {
  __builtin_amdgcn_global_load_lds((const __attribute__((address_space(1))) void*)g,
                                   (__attribute__((address_space(3))) void*)l, 16, 0, 0);
}

__global__ __launch_bounds__(256) void cvt_kernel(const float* __restrict__ in,
                                                  f16* __restrict__ out, int n) {
  int i = (blockIdx.x * 256 + threadIdx.x) * 8;
  if (i >= n) return;
  float4 a = *(const float4*)(in + i);
  float4 b = *(const float4*)(in + i + 4);
  f16x8 o;
  o[0] = (f16)a.x; o[1] = (f16)a.y; o[2] = (f16)a.z; o[3] = (f16)a.w;
  o[4] = (f16)b.x; o[5] = (f16)b.y; o[6] = (f16)b.z; o[7] = (f16)b.w;
  *(f16x8*)(out + i) = o;
}

// C = A @ B^T. A:[M][K] row-major f16, B:[N][K] row-major f16, fp32 accum.
// EPI 0: Q/K proj -> f16 [b,h,s,d] with bias + feature-mask
// EPI 1: V proj (A=Wv, B=v tokens) -> f16 Vt [b,h,d,s] with bias[R]
// EPI 2: O proj -> fp32 [M][N] + bias
template<int EPI>
__global__ __launch_bounds__(256) void gemm_f16(
    const f16* __restrict__ A, const f16* __restrict__ B,
    const float* __restrict__ bias, const int* __restrict__ mask,
    void* __restrict__ out, int M, int N, int K)
{
  __shared__ __align__(16) f16 lA[128 * 64];
  __shared__ __align__(16) f16 lB[128 * 64];
  const int tid = threadIdx.x;
  const int lane = tid & 63, wid = tid >> 6;
  const int wm = wid >> 1, wn = wid & 1;
  const int ln = lane & 15, lh = lane >> 4;
  const int bm = blockIdx.y, bn = blockIdx.x;

  // staging geometry: tile rows of 64 f16 = 8 x 16B slots; source slot
  // pre-swizzled (slot ^ row&7) so LDS holds the swizzled layout (rule #21).
  const int srow = tid >> 3;               // row within 32-row chunk group
  const int ssl  = (tid & 7) ^ (srow & 7); // source 16B slot
  const size_t Abase = (size_t)bm * 128 * K;
  const size_t Bbase = (size_t)bn * 128 * K;

  f32x4 acc[4][4] = {};

  for (int kt = 0; kt < K; kt += 64) {
#pragma unroll
    for (int c = 0; c < 4; ++c) {
      int L = c * 256 + tid;
      int row = c * 32 + srow;
      g2lds(A + Abase + (size_t)row * K + kt + ssl * 8, &lA[L * 8]);
      g2lds(B + Bbase + (size_t)row * K + kt + ssl * 8, &lB[L * 8]);
    }
    __syncthreads();
    f16x8 af[4][2], bf[4][2];
#pragma unroll
    for (int mf = 0; mf < 4; ++mf)
#pragma unroll
      for (int ks = 0; ks < 2; ++ks) {
        int r = wm * 64 + mf * 16 + ln;
        int sl = (ks * 4 + lh) ^ (ln & 7);
        af[mf][ks] = *(const f16x8*)&lA[r * 64 + sl * 8];
      }
#pragma unroll
    for (int nf = 0; nf < 4; ++nf)
#pragma unroll
      for (int ks = 0; ks < 2; ++ks) {
        int r = wn * 64 + nf * 16 + ln;
        int sl = (ks * 4 + lh) ^ (ln & 7);
        bf[nf][ks] = *(const f16x8*)&lB[r * 64 + sl * 8];
      }
#pragma unroll
    for (int mf = 0; mf < 4; ++mf)
#pragma unroll
      for (int nf = 0; nf < 4; ++nf)
#pragma unroll
        for (int ks = 0; ks < 2; ++ks)
          acc[mf][nf] = __builtin_amdgcn_mfma_f32_16x16x32_f16(
              af[mf][ks], bf[nf][ks], acc[mf][nf], 0, 0, 0);
    __syncthreads();
  }

#pragma unroll
  for (int mf = 0; mf < 4; ++mf)
#pragma unroll
    for (int nf = 0; nf < 4; ++nf)
#pragma unroll
      for (int i = 0; i < 4; ++i) {
        int R = bm * 128 + wm * 64 + mf * 16 + lh * 4 + i;
        int C = bn * 128 + wn * 64 + nf * 16 + ln;
        float v = acc[mf][nf][i];
        if (EPI == 0) {
          v += bias[C];
          v = mask[(R >> 8) * 256 + (C & 255)] ? v : 0.0f;
          ((f16*)out)[(size_t)((R >> 8) * 16 + (C >> 8)) * 65536 +
                      (size_t)(R & 255) * 256 + (C & 255)] = (f16)v;
        } else if (EPI == 1) {
          v += bias[R];
          ((f16*)out)[(size_t)(C >> 8) * 1048576 + (size_t)R * 256 + (C & 255)] = (f16)v;
        } else {
          v += bias[C];
          ((float*)out)[(size_t)R * N + C] = v;
        }
      }
}

// One block per (bh, 64-row q-block). Q:[bh][s][d], K:[bh][s][d] (masked),
// Vt:[bh][d][s]. aout: f16 [b*256+s][h*256+d] scaled by 1/64.
__global__ __launch_bounds__(256) void attn_kernel(
    const f16* __restrict__ Q, const f16* __restrict__ Kt,
    const f16* __restrict__ Vt, f16* __restrict__ aout)
{
  __shared__ __align__(16) f16 tile[64 * 256];
  __shared__ __align__(16) f16 pbuf[64 * 256];
  const int tid = threadIdx.x;
  const int lane = tid & 63, w = tid >> 6;
  const int ln = lane & 15, lh = lane >> 4;
  const int bh = blockIdx.x >> 2, rb = blockIdx.x & 3;
  const int b = bh >> 4, h = bh & 15;
  const size_t hb = (size_t)bh * 65536;

  // staging geometry for 64x256 f16 tiles (32 x 16B slots per row)
  const int strow = tid >> 5;                 // row within 8-row chunk group
  const int stsl  = (tid & 31) ^ (strow & 7); // pre-swizzled source slot

  // Q fragments straight from global (row-major, line-coalesced per 4 lanes)
  f16x8 aq[8];
  {
    const f16* qp = Q + hb + (size_t)(rb * 64 + w * 16 + ln) * 256;
#pragma unroll
    for (int ks = 0; ks < 8; ++ks)
      aq[ks] = *(const f16x8*)(qp + ks * 32 + lh * 8);
  }

  f32x4 sacc[16] = {};  // scores: 16 col-frags x (4 rows per lane)

  for (int kt = 0; kt < 4; ++kt) {
#pragma unroll
    for (int c = 0; c < 8; ++c) {
      int L = c * 256 + tid;
      int row = c * 8 + strow;
      g2lds(Kt + hb + (size_t)(kt * 64 + row) * 256 + stsl * 8, &tile[L * 8]);
    }
    __syncthreads();
#pragma unroll
    for (int nf = 0; nf < 4; ++nf) {
      f16x8 bf[8];
#pragma unroll
      for (int ks = 0; ks < 8; ++ks) {
        int r = nf * 16 + ln;
        int sl = (ks * 4 + lh) ^ (r & 7);
        bf[ks] = *(const f16x8*)&tile[r * 256 + sl * 8];
      }
#pragma unroll
      for (int ks = 0; ks < 8; ++ks)
        sacc[kt * 4 + nf] = __builtin_amdgcn_mfma_f32_16x16x32_f16(
            aq[ks], bf[ks], sacc[kt * 4 + nf], 0, 0, 0);
    }
    __syncthreads();
  }

  // in-register softmax; lane holds rows (lh*4+i), cols (ln + 16*frag)
  const float SC = 1.0f / 16.0f;
  float mrow[4] = {-1e30f, -1e30f, -1e30f, -1e30f};
#pragma unroll
  for (int t = 0; t < 16; ++t)
#pragma unroll
    for (int i = 0; i < 4; ++i) mrow[i] = fmaxf(mrow[i], sacc[t][i]);
#pragma unroll
  for (int i = 0; i < 4; ++i) {
    mrow[i] = fmaxf(mrow[i], __shfl_xor(mrow[i], 1));
    mrow[i] = fmaxf(mrow[i], __shfl_xor(mrow[i], 2));
    mrow[i] = fmaxf(mrow[i], __shfl_xor(mrow[i], 4));
    mrow[i] = fmaxf(mrow[i], __shfl_xor(mrow[i], 8));
  }
  float ssum[4] = {0.f, 0.f, 0.f, 0.f};
#pragma unroll
  for (int t = 0; t < 16; ++t)
#pragma unroll
    for (int i = 0; i < 4; ++i) {
      float p = __expf((sacc[t][i] - mrow[i]) * SC);
      sacc[t][i] = p;
      ssum[i] += p;
    }
#pragma unroll
  for (int i = 0; i < 4; ++i) {
    ssum[i] += __shfl_xor(ssum[i], 1);
    ssum[i] += __shfl_xor(ssum[i], 2);
    ssum[i] += __shfl_xor(ssum[i], 4);
    ssum[i] += __shfl_xor(ssum[i], 8);
  }
  float rs[4];
#pragma unroll
  for (int i = 0; i < 4; ++i) rs[i] = 1.0f / ssum[i];

  // write P to swizzled LDS (rows are wave-private: no barrier needed)
#pragma unroll
  for (int t = 0; t < 16; ++t)
#pragma unroll
    for (int i = 0; i < 4; ++i) {
      int row = w * 16 + lh * 4 + i;
      int col = (t >> 2) * 64 + (t & 3) * 16 + ln;
      pbuf[row * 256 + (col ^ ((row & 7) << 3))] = (f16)(sacc[t][i] * rs[i]);
    }

  // P A-fragments back from LDS (redistributed to MFMA-A layout)
  f16x8 pa[8];
  {
    int r = w * 16 + ln;
#pragma unroll
    for (int ks = 0; ks < 8; ++ks) {
      int col = ks * 32 + lh * 8;
      pa[ks] = *(const f16x8*)&pbuf[r * 256 + (col ^ ((r & 7) << 3))];
    }
  }

  for (int dt = 0; dt < 4; ++dt) {
#pragma unroll
    for (int c = 0; c < 8; ++c) {
      int L = c * 256 + tid;
      int row = c * 8 + strow;
      g2lds(Vt + hb + (size_t)(dt * 64 + row) * 256 + stsl * 8, &tile[L * 8]);
    }
    __syncthreads();
    f32x4 oacc[4] = {};
#pragma unroll
    for (int nf = 0; nf < 4; ++nf) {
      f16x8 bf[8];
#pragma unroll
      for (int ks = 0; ks < 8; ++ks) {
        int r = nf * 16 + ln;
        int sl = (ks * 4 + lh) ^ (r & 7);
        bf[ks] = *(const f16x8*)&tile[r * 256 + sl * 8];
      }
#pragma unroll
      for (int ks = 0; ks < 8; ++ks)
        oacc[nf] = __builtin_amdgcn_mfma_f32_16x16x32_f16(pa[ks], bf[ks], oacc[nf], 0, 0, 0);
    }
#pragma unroll
    for (int nf = 0; nf < 4; ++nf)
#pragma unroll
      for (int i = 0; i < 4; ++i) {
        int s = rb * 64 + w * 16 + lh * 4 + i;
        int d = dt * 64 + nf * 16 + ln;
        aout[(size_t)(b * 256 + s) * 4096 + h * 256 + d] = (f16)(oacc[nf][i] * 0.015625f);
      }
    __syncthreads();
  }
}

extern "C" void kernel_launch(void* const* d_in, const int* in_sizes, int n_in,
                              void* d_out, int out_size, void* d_ws, size_t ws_size,
                              hipStream_t stream) {
  const float* q  = (const float*)d_in[0];
  const float* k  = (const float*)d_in[1];
  const float* v  = (const float*)d_in[2];
  const int*   mk = (const int*)d_in[3];
  const float* Wq = (const float*)d_in[4];
  const float* bq = (const float*)d_in[5];
  const float* Wk = (const float*)d_in[6];
  const float* bk = (const float*)d_in[7];
  const float* Wv = (const float*)d_in[8];
  const float* bv = (const float*)d_in[9];
  const float* Wo = (const float*)d_in[10];
  const float* bo = (const float*)d_in[11];
  float* out = (float*)d_out;

  const size_t NQ = 2048ull * 4096;   // 8.4M
  const size_t NW = 4096ull * 4096;   // 16.8M
  f16* ws = (f16*)d_ws;
  f16* q16  = ws;
  f16* k16  = q16 + NQ;
  f16* v16  = k16 + NQ;
  f16* Wq16 = v16 + NQ;
  f16* Wk16 = Wq16 + NW;
  f16* Wv16 = Wk16 + NW;
  f16* Wo16 = Wv16 + NW;
  f16* Qbh  = Wo16 + NW;
  f16* Kbh  = Qbh + NQ;
  f16* Vt   = Kbh + NQ;
  f16* at16 = Vt + NQ;

  // fp32 -> fp16 converts
  cvt_kernel<<<(int)(NQ / 2048), 256, 0, stream>>>(q, q16, (int)NQ);
  cvt_kernel<<<(int)(NQ / 2048), 256, 0, stream>>>(k, k16, (int)NQ);
  cvt_kernel<<<(int)(NQ / 2048), 256, 0, stream>>>(v, v16, (int)NQ);
  cvt_kernel<<<(int)(NW / 2048), 256, 0, stream>>>(Wq, Wq16, (int)NW);
  cvt_kernel<<<(int)(NW / 2048), 256, 0, stream>>>(Wk, Wk16, (int)NW);
  cvt_kernel<<<(int)(NW / 2048), 256, 0, stream>>>(Wv, Wv16, (int)NW);
  cvt_kernel<<<(int)(NW / 2048), 256, 0, stream>>>(Wo, Wo16, (int)NW);

  // Q/K projections -> [b,h,s,d] f16, masked
  gemm_f16<0><<<dim3(32, 16), 256, 0, stream>>>(q16, Wq16, bq, mk, Qbh, 2048, 4096, 4096);
  gemm_f16<0><<<dim3(32, 16), 256, 0, stream>>>(k16, Wk16, bk, mk, Kbh, 2048, 4096, 4096);
  // V projection transposed: A=Wv [4096][4096], B=v [2048][4096] -> Vt [b,h,d,s]
  gemm_f16<1><<<dim3(16, 32), 256, 0, stream>>>(Wv16, v16, bv, nullptr, Vt, 4096, 2048, 4096);
  // attention
  attn_kernel<<<512, 256, 0, stream>>>(Qbh, Kbh, Vt, at16);
  // O projection -> fp32 output
  gemm_f16<2><<<dim3(32, 16), 256, 0, stream>>>(at16, Wo16, bo, nullptr, out, 2048, 4096, 4096);
}

// Round 2
// 410.194 us; speedup vs baseline: 1.2580x; 1.2580x over previous
//
#include <hip/hip_runtime.h>

// MultiHeadAttention: B=8, S=256, D=4096, H=16, HD=256 (fp32 in/out)
// fp32->fp16 converts; deep-pipelined fp16 MFMA GEMMs (counted vmcnt,
// 3-buffer LDS ring, T2 swizzle, T5 setprio); attention; O-proj -> fp32.

typedef _Float16 f16;
typedef f16 f16x8 __attribute__((ext_vector_type(8)));
typedef float f32x4 __attribute__((ext_vector_type(4)));

__device__ __forceinline__ void g2lds(const f16* g, f16* l) {
  __builtin_amdgcn_global_load_lds((const __attribute__((address_space(1))) void*)g,
                                   (__attribute__((address_space(3))) void*)l, 16, 0, 0);
}

__global__ __launch_bounds__(256) void cvt_kernel(const float* __restrict__ in,
                                                  f16* __restrict__ out, int n) {
  int i = (blockIdx.x * 256 + threadIdx.x) * 8;
  if (i >= n) return;
  float4 a = *(const float4*)(in + i);
  float4 b = *(const float4*)(in + i + 4);
  f16x8 o;
  o[0] = (f16)a.x; o[1] = (f16)a.y; o[2] = (f16)a.z; o[3] = (f16)a.w;
  o[4] = (f16)b.x; o[5] = (f16)b.y; o[6] = (f16)b.z; o[7] = (f16)b.w;
  *(f16x8*)(out + i) = o;
}

// C = A @ B^T. A:[M][K] f16 row-major, B:[N][K] f16 row-major, fp32 accum.
// Deep pipeline: tile 128x256, BK=64, 8 waves (2Mx4N, 64x64 each),
// 3-buffer LDS ring, counted vmcnt(6) (never 0 in main loop).
// EPI 0: Q/K proj -> f16 [b,h,s,d] + bias + feature-mask
// EPI 1: V proj (A=Wv, B=v) -> f16 Vt [b,h,d,s] + bias[R]
// EPI 2: O proj -> fp32 [M][N] + bias
template<int EPI>
__global__ __launch_bounds__(512, 2) void gemm_dp(
    const f16* __restrict__ A, const f16* __restrict__ B,
    const float* __restrict__ bias, const int* __restrict__ mask,
    void* __restrict__ out, int M, int N, int K)
{
  // per buffer: A 128x64 (8192 f16) + B 256x64 (16384 f16) = 24576 f16 (48KB)
  __shared__ __align__(16) f16 lds[3 * 24576];  // 144 KB
  const int tid = threadIdx.x;
  const int lane = tid & 63, wid = tid >> 6;
  const int wm = wid >> 2, wn = wid & 3;       // 2 x 4 waves
  const int ln = lane & 15, lh = lane >> 4;
  const int bm = blockIdx.y, bn = blockIdx.x;

  const size_t Abase = (size_t)bm * 128 * K;
  const size_t Bbase = (size_t)bn * 256 * K;

  // staging: row r = tid>>3 (+64j), source slot pre-swizzled (rule #21)
  const int sr = tid >> 3;
  const int ss = (tid & 7) ^ (sr & 7);

  const int NT = K >> 6;

#define STAGE(t, part)                                                          \
  do {                                                                          \
    const int kt_ = (t) << 6;                                                   \
    f16* bo_ = &lds[((t) % 3) * 24576];                                         \
    if ((part) == 0) {                                                          \
      g2lds(A + Abase + (size_t)sr * K + kt_ + ss * 8,         bo_ + tid * 8);  \
      g2lds(B + Bbase + (size_t)sr * K + kt_ + ss * 8,         bo_ + 8192 + tid * 8); \
      g2lds(B + Bbase + (size_t)(64 + sr) * K + kt_ + ss * 8,  bo_ + 8192 + (512 + tid) * 8); \
    } else {                                                                    \
      g2lds(A + Abase + (size_t)(64 + sr) * K + kt_ + ss * 8,  bo_ + (512 + tid) * 8); \
      g2lds(B + Bbase + (size_t)(128 + sr) * K + kt_ + ss * 8, bo_ + 8192 + (1024 + tid) * 8); \
      g2lds(B + Bbase + (size_t)(192 + sr) * K + kt_ + ss * 8, bo_ + 8192 + (1536 + tid) * 8); \
    }                                                                           \
  } while (0)

  f32x4 acc[4][4] = {};

  // prologue: stage tiles 0 and 1 (12 loads), wait tile 0 (6 outstanding left)
  STAGE(0, 0); STAGE(0, 1);
  STAGE(1, 0); STAGE(1, 1);
  asm volatile("s_waitcnt vmcnt(6)" ::: "memory");
  __builtin_amdgcn_s_barrier();

  const int sl0 = lh;        // ks=0 slot base (pre-XOR)
  const int sl1 = 4 + lh;    // ks=1
  const int lx = ln & 7;

  for (int t = 0; t < NT; ++t) {
    const f16* bA = &lds[(t % 3) * 24576];
    const f16* bB = bA + 8192;

    // ---- phase 0 (ks = 0) ----
    f16x8 a0[4], b0[4];
#pragma unroll
    for (int mf = 0; mf < 4; ++mf)
      a0[mf] = *(const f16x8*)&bA[(wm * 64 + mf * 16 + ln) * 64 + (sl0 ^ lx) * 8];
#pragma unroll
    for (int nf = 0; nf < 4; ++nf)
      b0[nf] = *(const f16x8*)&bB[(wn * 64 + nf * 16 + ln) * 64 + (sl0 ^ lx) * 8];
    if (t + 2 < NT) STAGE(t + 2, 0);
    asm volatile("" ::: "memory");
    __builtin_amdgcn_s_barrier();
    __builtin_amdgcn_s_setprio(1);
#pragma unroll
    for (int mf = 0; mf < 4; ++mf)
#pragma unroll
      for (int nf = 0; nf < 4; ++nf)
        acc[mf][nf] = __builtin_amdgcn_mfma_f32_16x16x32_f16(a0[mf], b0[nf], acc[mf][nf], 0, 0, 0);
    __builtin_amdgcn_s_setprio(0);
    asm volatile("" ::: "memory");
    __builtin_amdgcn_s_barrier();

    // ---- phase 1 (ks = 1) ----
    f16x8 a1[4], b1[4];
#pragma unroll
    for (int mf = 0; mf < 4; ++mf)
      a1[mf] = *(const f16x8*)&bA[(wm * 64 + mf * 16 + ln) * 64 + (sl1 ^ lx) * 8];
#pragma unroll
    for (int nf = 0; nf < 4; ++nf)
      b1[nf] = *(const f16x8*)&bB[(wn * 64 + nf * 16 + ln) * 64 + (sl1 ^ lx) * 8];
    if (t + 2 < NT) STAGE(t + 2, 1);
    asm volatile("" ::: "memory");
    __builtin_amdgcn_s_barrier();
    __builtin_amdgcn_s_setprio(1);
#pragma unroll
    for (int mf = 0; mf < 4; ++mf)
#pragma unroll
      for (int nf = 0; nf < 4; ++nf)
        acc[mf][nf] = __builtin_amdgcn_mfma_f32_16x16x32_f16(a1[mf], b1[nf], acc[mf][nf], 0, 0, 0);
    __builtin_amdgcn_s_setprio(0);
    // counted wait: retire tile t+1's 6 loads; keep t+2's 6 in flight
    if (t + 2 < NT) {
      asm volatile("s_waitcnt vmcnt(6)" ::: "memory");
    } else if (t + 1 < NT) {
      asm volatile("s_waitcnt vmcnt(0)" ::: "memory");
    }
    asm volatile("" ::: "memory");
    __builtin_amdgcn_s_barrier();
  }
#undef STAGE

#pragma unroll
  for (int mf = 0; mf < 4; ++mf)
#pragma unroll
    for (int nf = 0; nf < 4; ++nf)
#pragma unroll
      for (int i = 0; i < 4; ++i) {
        int R = bm * 128 + wm * 64 + mf * 16 + lh * 4 + i;
        int C = bn * 256 + wn * 64 + nf * 16 + ln;
        float v = acc[mf][nf][i];
        if (EPI == 0) {
          v += bias[C];
          v = mask[(R >> 8) * 256 + (C & 255)] ? v : 0.0f;
          ((f16*)out)[(size_t)((R >> 8) * 16 + (C >> 8)) * 65536 +
                      (size_t)(R & 255) * 256 + (C & 255)] = (f16)v;
        } else if (EPI == 1) {
          v += bias[R];
          ((f16*)out)[(size_t)(C >> 8) * 1048576 + (size_t)R * 256 + (C & 255)] = (f16)v;
        } else {
          v += bias[C];
          ((float*)out)[(size_t)R * N + C] = v;
        }
      }
}

// One block per (bh, 64-row q-block). Q:[bh][s][d], K:[bh][s][d] (masked),
// Vt:[bh][d][s]. aout: f16 [b*256+s][h*256+d] scaled by 1/64.
__global__ __launch_bounds__(256) void attn_kernel(
    const f16* __restrict__ Q, const f16* __restrict__ Kt,
    const f16* __restrict__ Vt, f16* __restrict__ aout)
{
  __shared__ __align__(16) f16 tile[64 * 256];
  __shared__ __align__(16) f16 pbuf[64 * 256];
  const int tid = threadIdx.x;
  const int lane = tid & 63, w = tid >> 6;
  const int ln = lane & 15, lh = lane >> 4;
  const int bh = blockIdx.x >> 2, rb = blockIdx.x & 3;
  const int b = bh >> 4, h = bh & 15;
  const size_t hb = (size_t)bh * 65536;

  const int strow = tid >> 5;
  const int stsl  = (tid & 31) ^ (strow & 7);

  f16x8 aq[8];
  {
    const f16* qp = Q + hb + (size_t)(rb * 64 + w * 16 + ln) * 256;
#pragma unroll
    for (int ks = 0; ks < 8; ++ks)
      aq[ks] = *(const f16x8*)(qp + ks * 32 + lh * 8);
  }

  f32x4 sacc[16] = {};

  for (int kt = 0; kt < 4; ++kt) {
#pragma unroll
    for (int c = 0; c < 8; ++c) {
      int L = c * 256 + tid;
      int row = c * 8 + strow;
      g2lds(Kt + hb + (size_t)(kt * 64 + row) * 256 + stsl * 8, &tile[L * 8]);
    }
    __syncthreads();
#pragma unroll
    for (int nf = 0; nf < 4; ++nf) {
      f16x8 bf[8];
#pragma unroll
      for (int ks = 0; ks < 8; ++ks) {
        int r = nf * 16 + ln;
        int sl = (ks * 4 + lh) ^ (r & 7);
        bf[ks] = *(const f16x8*)&tile[r * 256 + sl * 8];
      }
#pragma unroll
      for (int ks = 0; ks < 8; ++ks)
        sacc[kt * 4 + nf] = __builtin_amdgcn_mfma_f32_16x16x32_f16(
            aq[ks], bf[ks], sacc[kt * 4 + nf], 0, 0, 0);
    }
    __syncthreads();
  }

  const float SC = 1.0f / 16.0f;
  float mrow[4] = {-1e30f, -1e30f, -1e30f, -1e30f};
#pragma unroll
  for (int t = 0; t < 16; ++t)
#pragma unroll
    for (int i = 0; i < 4; ++i) mrow[i] = fmaxf(mrow[i], sacc[t][i]);
#pragma unroll
  for (int i = 0; i < 4; ++i) {
    mrow[i] = fmaxf(mrow[i], __shfl_xor(mrow[i], 1));
    mrow[i] = fmaxf(mrow[i], __shfl_xor(mrow[i], 2));
    mrow[i] = fmaxf(mrow[i], __shfl_xor(mrow[i], 4));
    mrow[i] = fmaxf(mrow[i], __shfl_xor(mrow[i], 8));
  }
  float ssum[4] = {0.f, 0.f, 0.f, 0.f};
#pragma unroll
  for (int t = 0; t < 16; ++t)
#pragma unroll
    for (int i = 0; i < 4; ++i) {
      float p = __expf((sacc[t][i] - mrow[i]) * SC);
      sacc[t][i] = p;
      ssum[i] += p;
    }
#pragma unroll
  for (int i = 0; i < 4; ++i) {
    ssum[i] += __shfl_xor(ssum[i], 1);
    ssum[i] += __shfl_xor(ssum[i], 2);
    ssum[i] += __shfl_xor(ssum[i], 4);
    ssum[i] += __shfl_xor(ssum[i], 8);
  }
  float rs[4];
#pragma unroll
  for (int i = 0; i < 4; ++i) rs[i] = 1.0f / ssum[i];

#pragma unroll
  for (int t = 0; t < 16; ++t)
#pragma unroll
    for (int i = 0; i < 4; ++i) {
      int row = w * 16 + lh * 4 + i;
      int col = (t >> 2) * 64 + (t & 3) * 16 + ln;
      pbuf[row * 256 + (col ^ ((row & 7) << 3))] = (f16)(sacc[t][i] * rs[i]);
    }

  f16x8 pa[8];
  {
    int r = w * 16 + ln;
#pragma unroll
    for (int ks = 0; ks < 8; ++ks) {
      int col = ks * 32 + lh * 8;
      pa[ks] = *(const f16x8*)&pbuf[r * 256 + (col ^ ((r & 7) << 3))];
    }
  }

  for (int dt = 0; dt < 4; ++dt) {
#pragma unroll
    for (int c = 0; c < 8; ++c) {
      int L = c * 256 + tid;
      int row = c * 8 + strow;
      g2lds(Vt + hb + (size_t)(dt * 64 + row) * 256 + stsl * 8, &tile[L * 8]);
    }
    __syncthreads();
    f32x4 oacc[4] = {};
#pragma unroll
    for (int nf = 0; nf < 4; ++nf) {
      f16x8 bf[8];
#pragma unroll
      for (int ks = 0; ks < 8; ++ks) {
        int r = nf * 16 + ln;
        int sl = (ks * 4 + lh) ^ (r & 7);
        bf[ks] = *(const f16x8*)&tile[r * 256 + sl * 8];
      }
#pragma unroll
      for (int ks = 0; ks < 8; ++ks)
        oacc[nf] = __builtin_amdgcn_mfma_f32_16x16x32_f16(pa[ks], bf[ks], oacc[nf], 0, 0, 0);
    }
#pragma unroll
    for (int nf = 0; nf < 4; ++nf)
#pragma unroll
      for (int i = 0; i < 4; ++i) {
        int s = rb * 64 + w * 16 + lh * 4 + i;
        int d = dt * 64 + nf * 16 + ln;
        aout[(size_t)(b * 256 + s) * 4096 + h * 256 + d] = (f16)(oacc[nf][i] * 0.015625f);
      }
    __syncthreads();
  }
}

extern "C" void kernel_launch(void* const* d_in, const int* in_sizes, int n_in,
                              void* d_out, int out_size, void* d_ws, size_t ws_size,
                              hipStream_t stream) {
  const float* q  = (const float*)d_in[0];
  const float* k  = (const float*)d_in[1];
  const float* v  = (const float*)d_in[2];
  const int*   mk = (const int*)d_in[3];
  const float* Wq = (const float*)d_in[4];
  const float* bq = (const float*)d_in[5];
  const float* Wk = (const float*)d_in[6];
  const float* bk = (const float*)d_in[7];
  const float* Wv = (const float*)d_in[8];
  const float* bv = (const float*)d_in[9];
  const float* Wo = (const float*)d_in[10];
  const float* bo = (const float*)d_in[11];
  float* out = (float*)d_out;

  const size_t NQ = 2048ull * 4096;
  const size_t NW = 4096ull * 4096;
  f16* ws = (f16*)d_ws;
  f16* q16  = ws;
  f16* k16  = q16 + NQ;
  f16* v16  = k16 + NQ;
  f16* Wq16 = v16 + NQ;
  f16* Wk16 = Wq16 + NW;
  f16* Wv16 = Wk16 + NW;
  f16* Wo16 = Wv16 + NW;
  f16* Qbh  = Wo16 + NW;
  f16* Kbh  = Qbh + NQ;
  f16* Vt   = Kbh + NQ;
  f16* at16 = Vt + NQ;

  cvt_kernel<<<(int)(NQ / 2048), 256, 0, stream>>>(q, q16, (int)NQ);
  cvt_kernel<<<(int)(NQ / 2048), 256, 0, stream>>>(k, k16, (int)NQ);
  cvt_kernel<<<(int)(NQ / 2048), 256, 0, stream>>>(v, v16, (int)NQ);
  cvt_kernel<<<(int)(NW / 2048), 256, 0, stream>>>(Wq, Wq16, (int)NW);
  cvt_kernel<<<(int)(NW / 2048), 256, 0, stream>>>(Wk, Wk16, (int)NW);
  cvt_kernel<<<(int)(NW / 2048), 256, 0, stream>>>(Wv, Wv16, (int)NW);
  cvt_kernel<<<(int)(NW / 2048), 256, 0, stream>>>(Wo, Wo16, (int)NW);

  // Q/K projections -> [b,h,s,d] f16, masked. grid = (N/256, M/128)
  gemm_dp<0><<<dim3(16, 16), 512, 0, stream>>>(q16, Wq16, bq, mk, Qbh, 2048, 4096, 4096);
  gemm_dp<0><<<dim3(16, 16), 512, 0, stream>>>(k16, Wk16, bk, mk, Kbh, 2048, 4096, 4096);
  // V projection transposed: A=Wv [4096][4096], B=v [2048][4096] -> Vt [b,h,d,s]
  gemm_dp<1><<<dim3(8, 32), 512, 0, stream>>>(Wv16, v16, bv, nullptr, Vt, 4096, 2048, 4096);
  attn_kernel<<<512, 256, 0, stream>>>(Qbh, Kbh, Vt, at16);
  gemm_dp<2><<<dim3(16, 16), 512, 0, stream>>>(at16, Wo16, bo, nullptr, out, 2048, 4096, 4096);
}

// Round 3
// 403.011 us; speedup vs baseline: 1.2804x; 1.0178x over previous
//
#include <hip/hip_runtime.h>

// MultiHeadAttention: B=8, S=256, D=4096, H=16, HD=256 (fp32 in/out)
// fp32->fp16 converts; deep-pipelined fp16 MFMA GEMMs (3-buffer LDS ring,
// counted vmcnt, register-fragment double-buffer so ds_read overlaps MFMA);
// attention; O-proj -> fp32.

typedef _Float16 f16;
typedef f16 f16x8 __attribute__((ext_vector_type(8)));
typedef float f32x4 __attribute__((ext_vector_type(4)));

__device__ __forceinline__ void g2lds(const f16* g, f16* l) {
  __builtin_amdgcn_global_load_lds((const __attribute__((address_space(1))) void*)g,
                                   (__attribute__((address_space(3))) void*)l, 16, 0, 0);
}

__global__ __launch_bounds__(256) void cvt_kernel(const float* __restrict__ in,
                                                  f16* __restrict__ out, int n) {
  int i = (blockIdx.x * 256 + threadIdx.x) * 8;
  if (i >= n) return;
  float4 a = *(const float4*)(in + i);
  float4 b = *(const float4*)(in + i + 4);
  f16x8 o;
  o[0] = (f16)a.x; o[1] = (f16)a.y; o[2] = (f16)a.z; o[3] = (f16)a.w;
  o[4] = (f16)b.x; o[5] = (f16)b.y; o[6] = (f16)b.z; o[7] = (f16)b.w;
  *(f16x8*)(out + i) = o;
}

// C = A @ B^T. A:[M][K] f16 row-major, B:[N][K] f16 row-major, fp32 accum.
// Tile 128x256, BK=64, 8 waves (2Mx4N, 64x64 each), 3-buffer LDS ring,
// counted vmcnt(6), register-fragment double-buffer (ds_read || MFMA).
// EPI 0: Q/K proj -> f16 [b,h,s,d] + bias + feature-mask
// EPI 1: V proj (A=Wv, B=v) -> f16 Vt [b,h,d,s] + bias[R]
// EPI 2: O proj -> fp32 [M][N] + bias
template<int EPI>
__global__ __launch_bounds__(512, 2) void gemm_dp(
    const f16* __restrict__ A, const f16* __restrict__ B,
    const float* __restrict__ bias, const int* __restrict__ mask,
    void* __restrict__ out, int M, int N, int K)
{
  // per buffer: A 128x64 (8192 f16) + B 256x64 (16384 f16) = 24576 f16 (48KB)
  __shared__ __align__(16) f16 lds[3 * 24576];  // 144 KB
  const int tid = threadIdx.x;
  const int lane = tid & 63, wid = tid >> 6;
  const int wm = wid >> 2, wn = wid & 3;       // 2 x 4 waves
  const int ln = lane & 15, lh = lane >> 4;
  const int bm = blockIdx.y, bn = blockIdx.x;

  const size_t Abase = (size_t)bm * 128 * K;
  const size_t Bbase = (size_t)bn * 256 * K;

  // staging: row r = tid>>3 (+64j), source slot pre-swizzled (rule #21)
  const int sr = tid >> 3;
  const int ss = (tid & 7) ^ (sr & 7);

  const int NT = K >> 6;

  f16* p0 = &lds[0];          // buffer for tile t
  f16* p1 = &lds[24576];      // tile t+1
  f16* p2 = &lds[2 * 24576];  // tile t+2 (staging target)

#define STAGE(t_, bo_, part)                                                    \
  do {                                                                          \
    const int kt_ = (t_) << 6;                                                  \
    if ((part) == 0) {                                                          \
      g2lds(A + Abase + (size_t)sr * K + kt_ + ss * 8,         (bo_) + tid * 8);  \
      g2lds(B + Bbase + (size_t)sr * K + kt_ + ss * 8,         (bo_) + 8192 + tid * 8); \
      g2lds(B + Bbase + (size_t)(64 + sr) * K + kt_ + ss * 8,  (bo_) + 8192 + (512 + tid) * 8); \
    } else {                                                                    \
      g2lds(A + Abase + (size_t)(64 + sr) * K + kt_ + ss * 8,  (bo_) + (512 + tid) * 8); \
      g2lds(B + Bbase + (size_t)(128 + sr) * K + kt_ + ss * 8, (bo_) + 8192 + (1024 + tid) * 8); \
      g2lds(B + Bbase + (size_t)(192 + sr) * K + kt_ + ss * 8, (bo_) + 8192 + (1536 + tid) * 8); \
    }                                                                           \
  } while (0)

  const int lx = ln & 7;
  const int arow = (wm * 64 + ln) * 64;   // A frag row base (f16 idx), +mf*16*64
  const int brow = (wn * 64 + ln) * 64;

#define LOADFRAGS(fa, fb, buf, ks)                                              \
  do {                                                                          \
    const f16* bA_ = (buf);                                                     \
    const f16* bB_ = (buf) + 8192;                                              \
    const int so_ = (((ks) * 4 + lh) ^ lx) * 8;                                 \
    _Pragma("unroll")                                                           \
    for (int mf = 0; mf < 4; ++mf)                                              \
      fa[mf] = *(const f16x8*)&bA_[arow + mf * 1024 + so_];                     \
    _Pragma("unroll")                                                           \
    for (int nf = 0; nf < 4; ++nf)                                              \
      fb[nf] = *(const f16x8*)&bB_[brow + nf * 1024 + so_];                     \
  } while (0)

#define MFMA16(fa, fb)                                                          \
  do {                                                                          \
    __builtin_amdgcn_s_setprio(1);                                              \
    _Pragma("unroll")                                                           \
    for (int mf = 0; mf < 4; ++mf)                                              \
      _Pragma("unroll")                                                         \
      for (int nf = 0; nf < 4; ++nf)                                            \
        acc[mf][nf] = __builtin_amdgcn_mfma_f32_16x16x32_f16(fa[mf], fb[nf],    \
                                                             acc[mf][nf], 0, 0, 0); \
    __builtin_amdgcn_s_setprio(0);                                              \
  } while (0)

  f32x4 acc[4][4] = {};
  f16x8 ca[4], cb[4], na[4], nb[4];

  // prologue: stage tiles 0,1 (12 loads); wait tile 0 (6 left in flight)
  STAGE(0, p0, 0); STAGE(0, p0, 1);
  STAGE(1, p1, 0); STAGE(1, p1, 1);
  asm volatile("s_waitcnt vmcnt(6)" ::: "memory");
  __builtin_amdgcn_s_barrier();
  asm volatile("" ::: "memory");
  LOADFRAGS(ca, cb, p0, 0);   // R0(0) in flight

  for (int t = 0; t < NT; ++t) {
    // ---- phase A: issue R1(t) + stage t+2, MFMA on R0(t) ----
    LOADFRAGS(na, nb, p0, 1);
    if (t + 2 < NT) { STAGE(t + 2, p2, 0); STAGE(t + 2, p2, 1); }
    MFMA16(ca, cb);           // compiler: lgkmcnt(8) -> waits cur only

    // ---- phase B: rotate to t+1, issue R0(t+1), MFMA on R1(t) ----
    if (t + 1 < NT) {
      if (t + 2 < NT) {
        asm volatile("s_waitcnt vmcnt(6)" ::: "memory");   // tile t+1 staged
      } else {
        asm volatile("s_waitcnt vmcnt(0)" ::: "memory");
      }
      __builtin_amdgcn_s_barrier();
      asm volatile("" ::: "memory");
      LOADFRAGS(ca, cb, p1, 0);
      MFMA16(na, nb);         // compiler: lgkmcnt(8) -> waits nxt only
      asm volatile("" ::: "memory");
      __builtin_amdgcn_s_barrier();   // all R1(t) reads done -> buf t re-stageable
      asm volatile("" ::: "memory");
      f16* tp = p0; p0 = p1; p1 = p2; p2 = tp;
    } else {
      MFMA16(na, nb);
    }
  }
#undef STAGE
#undef LOADFRAGS
#undef MFMA16

#pragma unroll
  for (int mf = 0; mf < 4; ++mf)
#pragma unroll
    for (int nf = 0; nf < 4; ++nf)
#pragma unroll
      for (int i = 0; i < 4; ++i) {
        int R = bm * 128 + wm * 64 + mf * 16 + lh * 4 + i;
        int C = bn * 256 + wn * 64 + nf * 16 + ln;
        float v = acc[mf][nf][i];
        if (EPI == 0) {
          v += bias[C];
          v = mask[(R >> 8) * 256 + (C & 255)] ? v : 0.0f;
          ((f16*)out)[(size_t)((R >> 8) * 16 + (C >> 8)) * 65536 +
                      (size_t)(R & 255) * 256 + (C & 255)] = (f16)v;
        } else if (EPI == 1) {
          v += bias[R];
          ((f16*)out)[(size_t)(C >> 8) * 1048576 + (size_t)R * 256 + (C & 255)] = (f16)v;
        } else {
          v += bias[C];
          ((float*)out)[(size_t)R * N + C] = v;
        }
      }
}

// One block per (bh, 64-row q-block). Q:[bh][s][d], K:[bh][s][d] (masked),
// Vt:[bh][d][s]. aout: f16 [b*256+s][h*256+d] scaled by 1/64.
__global__ __launch_bounds__(256) void attn_kernel(
    const f16* __restrict__ Q, const f16* __restrict__ Kt,
    const f16* __restrict__ Vt, f16* __restrict__ aout)
{
  __shared__ __align__(16) f16 tile[64 * 256];
  __shared__ __align__(16) f16 pbuf[64 * 256];
  const int tid = threadIdx.x;
  const int lane = tid & 63, w = tid >> 6;
  const int ln = lane & 15, lh = lane >> 4;
  const int bh = blockIdx.x >> 2, rb = blockIdx.x & 3;
  const int b = bh >> 4, h = bh & 15;
  const size_t hb = (size_t)bh * 65536;

  const int strow = tid >> 5;
  const int stsl  = (tid & 31) ^ (strow & 7);

  f16x8 aq[8];
  {
    const f16* qp = Q + hb + (size_t)(rb * 64 + w * 16 + ln) * 256;
#pragma unroll
    for (int ks = 0; ks < 8; ++ks)
      aq[ks] = *(const f16x8*)(qp + ks * 32 + lh * 8);
  }

  f32x4 sacc[16] = {};

  for (int kt = 0; kt < 4; ++kt) {
#pragma unroll
    for (int c = 0; c < 8; ++c) {
      int L = c * 256 + tid;
      int row = c * 8 + strow;
      g2lds(Kt + hb + (size_t)(kt * 64 + row) * 256 + stsl * 8, &tile[L * 8]);
    }
    __syncthreads();
#pragma unroll
    for (int nf = 0; nf < 4; ++nf) {
      f16x8 bf[8];
#pragma unroll
      for (int ks = 0; ks < 8; ++ks) {
        int r = nf * 16 + ln;
        int sl = (ks * 4 + lh) ^ (r & 7);
        bf[ks] = *(const f16x8*)&tile[r * 256 + sl * 8];
      }
#pragma unroll
      for (int ks = 0; ks < 8; ++ks)
        sacc[kt * 4 + nf] = __builtin_amdgcn_mfma_f32_16x16x32_f16(
            aq[ks], bf[ks], sacc[kt * 4 + nf], 0, 0, 0);
    }
    __syncthreads();
  }

  const float SC = 1.0f / 16.0f;
  float mrow[4] = {-1e30f, -1e30f, -1e30f, -1e30f};
#pragma unroll
  for (int t = 0; t < 16; ++t)
#pragma unroll
    for (int i = 0; i < 4; ++i) mrow[i] = fmaxf(mrow[i], sacc[t][i]);
#pragma unroll
  for (int i = 0; i < 4; ++i) {
    mrow[i] = fmaxf(mrow[i], __shfl_xor(mrow[i], 1));
    mrow[i] = fmaxf(mrow[i], __shfl_xor(mrow[i], 2));
    mrow[i] = fmaxf(mrow[i], __shfl_xor(mrow[i], 4));
    mrow[i] = fmaxf(mrow[i], __shfl_xor(mrow[i], 8));
  }
  float ssum[4] = {0.f, 0.f, 0.f, 0.f};
#pragma unroll
  for (int t = 0; t < 16; ++t)
#pragma unroll
    for (int i = 0; i < 4; ++i) {
      float p = __expf((sacc[t][i] - mrow[i]) * SC);
      sacc[t][i] = p;
      ssum[i] += p;
    }
#pragma unroll
  for (int i = 0; i < 4; ++i) {
    ssum[i] += __shfl_xor(ssum[i], 1);
    ssum[i] += __shfl_xor(ssum[i], 2);
    ssum[i] += __shfl_xor(ssum[i], 4);
    ssum[i] += __shfl_xor(ssum[i], 8);
  }
  float rs[4];
#pragma unroll
  for (int i = 0; i < 4; ++i) rs[i] = 1.0f / ssum[i];

#pragma unroll
  for (int t = 0; t < 16; ++t)
#pragma unroll
    for (int i = 0; i < 4; ++i) {
      int row = w * 16 + lh * 4 + i;
      int col = (t >> 2) * 64 + (t & 3) * 16 + ln;
      pbuf[row * 256 + (col ^ ((row & 7) << 3))] = (f16)(sacc[t][i] * rs[i]);
    }

  f16x8 pa[8];
  {
    int r = w * 16 + ln;
#pragma unroll
    for (int ks = 0; ks < 8; ++ks) {
      int col = ks * 32 + lh * 8;
      pa[ks] = *(const f16x8*)&pbuf[r * 256 + (col ^ ((r & 7) << 3))];
    }
  }

  for (int dt = 0; dt < 4; ++dt) {
#pragma unroll
    for (int c = 0; c < 8; ++c) {
      int L = c * 256 + tid;
      int row = c * 8 + strow;
      g2lds(Vt + hb + (size_t)(dt * 64 + row) * 256 + stsl * 8, &tile[L * 8]);
    }
    __syncthreads();
    f32x4 oacc[4] = {};
#pragma unroll
    for (int nf = 0; nf < 4; ++nf) {
      f16x8 bf[8];
#pragma unroll
      for (int ks = 0; ks < 8; ++ks) {
        int r = nf * 16 + ln;
        int sl = (ks * 4 + lh) ^ (r & 7);
        bf[ks] = *(const f16x8*)&tile[r * 256 + sl * 8];
      }
#pragma unroll
      for (int ks = 0; ks < 8; ++ks)
        oacc[nf] = __builtin_amdgcn_mfma_f32_16x16x32_f16(pa[ks], bf[ks], oacc[nf], 0, 0, 0);
    }
#pragma unroll
    for (int nf = 0; nf < 4; ++nf)
#pragma unroll
      for (int i = 0; i < 4; ++i) {
        int s = rb * 64 + w * 16 + lh * 4 + i;
        int d = dt * 64 + nf * 16 + ln;
        aout[(size_t)(b * 256 + s) * 4096 + h * 256 + d] = (f16)(oacc[nf][i] * 0.015625f);
      }
    __syncthreads();
  }
}

extern "C" void kernel_launch(void* const* d_in, const int* in_sizes, int n_in,
                              void* d_out, int out_size, void* d_ws, size_t ws_size,
                              hipStream_t stream) {
  const float* q  = (const float*)d_in[0];
  const float* k  = (const float*)d_in[1];
  const float* v  = (const float*)d_in[2];
  const int*   mk = (const int*)d_in[3];
  const float* Wq = (const float*)d_in[4];
  const float* bq = (const float*)d_in[5];
  const float* Wk = (const float*)d_in[6];
  const float* bk = (const float*)d_in[7];
  const float* Wv = (const float*)d_in[8];
  const float* bv = (const float*)d_in[9];
  const float* Wo = (const float*)d_in[10];
  const float* bo = (const float*)d_in[11];
  float* out = (float*)d_out;

  const size_t NQ = 2048ull * 4096;
  const size_t NW = 4096ull * 4096;
  f16* ws = (f16*)d_ws;
  f16* q16  = ws;
  f16* k16  = q16 + NQ;
  f16* v16  = k16 + NQ;
  f16* Wq16 = v16 + NQ;
  f16* Wk16 = Wq16 + NW;
  f16* Wv16 = Wk16 + NW;
  f16* Wo16 = Wv16 + NW;
  f16* Qbh  = Wo16 + NW;
  f16* Kbh  = Qbh + NQ;
  f16* Vt   = Kbh + NQ;
  f16* at16 = Vt + NQ;

  cvt_kernel<<<(int)(NQ / 2048), 256, 0, stream>>>(q, q16, (int)NQ);
  cvt_kernel<<<(int)(NQ / 2048), 256, 0, stream>>>(k, k16, (int)NQ);
  cvt_kernel<<<(int)(NQ / 2048), 256, 0, stream>>>(v, v16, (int)NQ);
  cvt_kernel<<<(int)(NW / 2048), 256, 0, stream>>>(Wq, Wq16, (int)NW);
  cvt_kernel<<<(int)(NW / 2048), 256, 0, stream>>>(Wk, Wk16, (int)NW);
  cvt_kernel<<<(int)(NW / 2048), 256, 0, stream>>>(Wv, Wv16, (int)NW);
  cvt_kernel<<<(int)(NW / 2048), 256, 0, stream>>>(Wo, Wo16, (int)NW);

  // Q/K projections -> [b,h,s,d] f16, masked. grid = (N/256, M/128)
  gemm_dp<0><<<dim3(16, 16), 512, 0, stream>>>(q16, Wq16, bq, mk, Qbh, 2048, 4096, 4096);
  gemm_dp<0><<<dim3(16, 16), 512, 0, stream>>>(k16, Wk16, bk, mk, Kbh, 2048, 4096, 4096);
  // V projection transposed: A=Wv [4096][4096], B=v [2048][4096] -> Vt [b,h,d,s]
  gemm_dp<1><<<dim3(8, 32), 512, 0, stream>>>(Wv16, v16, bv, nullptr, Vt, 4096, 2048, 4096);
  attn_kernel<<<512, 256, 0, stream>>>(Qbh, Kbh, Vt, at16);
  gemm_dp<2><<<dim3(16, 16), 512, 0, stream>>>(at16, Wo16, bo, nullptr, out, 2048, 4096, 4096);
}